// Round 2
// baseline (98.626 us; speedup 1.0000x reference)
//
#include <hip/hip_runtime.h>
#include <float.h>

#define OUTP 7
#define NCH 256
#define FH 50
#define FW 50
#define CPB 4   // channels per block (one per wave)

__global__ __launch_bounds__(256) void roi_pool_opt(
    const float* __restrict__ features,   // (B,256,50,50)
    const float* __restrict__ cat_rois,   // (N,5): im,x1,y1,x2,y2
    float* __restrict__ out)              // (N,256,7,7)
{
    __shared__ float lds[CPB][FH * FW];   // 4 * 10000 B = 40000 B

    const int n    = blockIdx.x;          // ROI index
    const int lane = threadIdx.x & 63;
    const int quad = threadIdx.x >> 6;    // which wave -> which channel
    const int c    = blockIdx.y * CPB + quad;

    const float* r5 = cat_rois + n * 5;
    const int im = (int)rintf(r5[0]);
    const int x1 = (int)rintf(r5[1] * 0.0625f);
    const int y1 = (int)rintf(r5[2] * 0.0625f);
    const int x2 = (int)rintf(r5[3] * 0.0625f);
    const int y2 = (int)rintf(r5[4] * 0.0625f);

    const int h = y2 - y1 + 1;            // >= 1, region fully in-bounds
    const int w = x2 - x1 + 1;

    // ---- Phase A: stage region [y1..y2]x[x1..x2] into LDS (coalesced,
    //      independent row loads; lanes map to consecutive x) ----
    const float* base = features + ((size_t)(im * NCH + c)) * (FH * FW)
                                 + y1 * FW + x1;
    float* ldsq = lds[quad];
    if (lane < w) {
        for (int r = 0; r < h; ++r) {
            ldsq[r * w + lane] = base[r * FW + lane];
        }
    }
    __syncthreads();   // lgkmcnt/vmcnt drain; cross-lane LDS visibility

    // ---- Phase B: 49 lanes compute the 7x7 bin maxima from LDS ----
    if (lane < OUTP * OUTP) {
        const int i = lane / OUTP;
        const int j = lane % OUTP;
        // bin bounds relative to (y1,x1); reference clamp is a no-op here
        const int ys = i * h / OUTP;
        const int ye = ((i + 1) * h + OUTP - 1) / OUTP;
        const int xs = j * w / OUTP;
        const int xe = ((j + 1) * w + OUTP - 1) / OUTP;

        float m = -FLT_MAX;
        for (int r = ys; r < ye; ++r) {
            const float* row = ldsq + r * w;
            for (int x = xs; x < xe; ++x) {
                m = fmaxf(m, row[x]);
            }
        }
        out[(((size_t)n * NCH + c) * OUTP + i) * OUTP + j] = m;
    }
}

extern "C" void kernel_launch(void* const* d_in, const int* in_sizes, int n_in,
                              void* d_out, int out_size, void* d_ws, size_t ws_size,
                              hipStream_t stream) {
    const float* features = (const float*)d_in[0];
    const float* cat_rois = (const float*)d_in[1];
    float* out = (float*)d_out;

    const int N = in_sizes[1] / 5;        // 128 ROIs
    dim3 grid(N, NCH / CPB);              // 128 x 64 = 8192 blocks
    roi_pool_opt<<<grid, 256, 0, stream>>>(features, cat_rois, out);
}